// Round 2
// baseline (827.061 us; speedup 1.0000x reference)
//
#include <hip/hip_runtime.h>
#include <hip/hip_bf16.h>

typedef unsigned int uint;
typedef unsigned short ushort;

#define NN 65536
#define NE 1048576
#define DD 128
#define TOTE (NE + NN)   // 1114112

__device__ __forceinline__ float b2f(ushort u) {
    uint v = ((uint)u) << 16; float f; __builtin_memcpy(&f, &v, 4); return f;
}
__device__ __forceinline__ ushort f2b(float f) {
    uint x; __builtin_memcpy(&x, &f, 4);
    uint r = (x + 0x7fffu + ((x >> 16) & 1u)) >> 16;
    return (ushort)r;
}

typedef __bf16 bf16x8 __attribute__((ext_vector_type(8)));
typedef float f32x4 __attribute__((ext_vector_type(4)));

// ---------- mean of edge_attr ----------
__global__ void k_sum(const float* __restrict__ ea, float* __restrict__ sum) {
    __shared__ float red[256];
    int t = threadIdx.x;
    float s = 0.f;
    for (int i = blockIdx.x * 256 + t; i < NE; i += gridDim.x * 256) s += ea[i];
    red[t] = s; __syncthreads();
    for (int o = 128; o > 0; o >>= 1) { if (t < o) red[t] += red[t + o]; __syncthreads(); }
    if (t == 0) atomicAdd(sum, red[0]);
}

// ---------- CSR build ----------
__global__ void k_hist(const int* __restrict__ dst, int* __restrict__ cnt) {
    int e = blockIdx.x * 256 + threadIdx.x;   // grid covers TOTE exactly
    int d = (e < NE) ? dst[e] : (e - NE);
    atomicAdd(&cnt[d], 1);
}

__global__ void k_scanA(const int* __restrict__ cnt, int* __restrict__ row_off, int* __restrict__ bsum) {
    __shared__ int tmp[256];
    int t = threadIdx.x, i = blockIdx.x * 256 + t;
    int v = cnt[i]; tmp[t] = v; __syncthreads();
    for (int off = 1; off < 256; off <<= 1) {
        int x = (t >= off) ? tmp[t - off] : 0;
        __syncthreads();
        tmp[t] += x;
        __syncthreads();
    }
    row_off[i] = tmp[t] - v;
    if (t == 255) bsum[blockIdx.x] = tmp[255];
}

__global__ void k_scanB(int* __restrict__ bsum) {
    __shared__ int tmp[256];
    int t = threadIdx.x;
    int v = bsum[t]; tmp[t] = v; __syncthreads();
    for (int off = 1; off < 256; off <<= 1) {
        int x = (t >= off) ? tmp[t - off] : 0;
        __syncthreads();
        tmp[t] += x;
        __syncthreads();
    }
    bsum[t] = tmp[t] - v;
}

__global__ void k_scanC(int* __restrict__ row_off, const int* __restrict__ bsum, int* __restrict__ cursor) {
    int i = blockIdx.x * 256 + threadIdx.x;
    int v = row_off[i] + bsum[blockIdx.x];
    row_off[i] = v;
    cursor[i] = v;
    if (i == 0) row_off[NN] = TOTE;
}

__global__ void k_scatter(const int* __restrict__ src, const int* __restrict__ dst,
                          const float* __restrict__ ea, const float* __restrict__ sum,
                          int* __restrict__ cursor, int* __restrict__ adj_src, float* __restrict__ adj_ea) {
    int e = blockIdx.x * 256 + threadIdx.x;   // grid covers TOTE exactly
    int s, d; float a;
    if (e < NE) { s = src[e]; d = dst[e]; a = ea[e]; }
    else        { s = e - NE; d = s;      a = sum[0] * (1.0f / NE); }
    int pos = atomicAdd(&cursor[d], 1);
    adj_src[pos] = s;
    adj_ea[pos] = a;
}

// ---------- per-layer: transpose W (fp32 k-major -> bf16 n-major) ----------
__global__ void k_transpose(const float* __restrict__ Wl, const float* __restrict__ Wr,
                            ushort* __restrict__ WT) {
    // grid (128, 2), block 128
    int k = blockIdx.x, n = threadIdx.x;
    const float* W = blockIdx.y ? Wr : Wl;
    WT[blockIdx.y * 16384 + n * 128 + k] = f2b(W[k * 128 + n]);
}

// ---------- dual GEMM: xl = h@Wl + bl, xr = h@Wr + br  (bf16 MFMA 16x16x32) ----------
#define LDA 136   // bf16 elems per A row in LDS (272B stride, 16B aligned)

__global__ __launch_bounds__(256) void k_gemm(const float* __restrict__ h, const ushort* __restrict__ WT,
                                              const float* __restrict__ bl, const float* __restrict__ br,
                                              ushort* __restrict__ xl, ushort* __restrict__ xr) {
    __shared__ ushort A[64 * LDA];
    int t = threadIdx.x;
    int rowbase = blockIdx.x * 64;

    for (int idx = t; idx < 64 * 128; idx += 256) {
        int r = idx >> 7, c = idx & 127;
        A[r * LDA + c] = f2b(h[(size_t)(rowbase + r) * 128 + c]);
    }
    __syncthreads();

    int wave = t >> 6, lane = t & 63;
    int row16 = lane & 15, quad = lane >> 4;

    f32x4 accl[8], accr[8];
    for (int i = 0; i < 8; i++) {
        accl[i] = (f32x4){0.f, 0.f, 0.f, 0.f};
        accr[i] = (f32x4){0.f, 0.f, 0.f, 0.f};
    }

    for (int ks = 0; ks < 4; ks++) {
        bf16x8 a = *(const bf16x8*)&A[(wave * 16 + row16) * LDA + ks * 32 + quad * 8];
        for (int tc = 0; tc < 8; tc++) {
            int coln = tc * 16 + row16;                 // B fragment: n = lane&15
            bf16x8 b_l = *(const bf16x8*)&WT[coln * 128 + ks * 32 + quad * 8];
            bf16x8 b_r = *(const bf16x8*)&WT[16384 + coln * 128 + ks * 32 + quad * 8];
            accl[tc] = __builtin_amdgcn_mfma_f32_16x16x32_bf16(a, b_l, accl[tc], 0, 0, 0);
            accr[tc] = __builtin_amdgcn_mfma_f32_16x16x32_bf16(a, b_r, accr[tc], 0, 0, 0);
        }
    }

    for (int tc = 0; tc < 8; tc++) {
        int col = tc * 16 + row16;                      // C/D: col = lane&15
        float bbl = bl[col], bbr = br[col];
        for (int r = 0; r < 4; r++) {
            int row = rowbase + wave * 16 + quad * 4 + r;   // C/D: row = quad*4 + reg
            size_t o = (size_t)row * 128 + col;
            xl[o] = f2b(accl[tc][r] + bbl);
            xr[o] = f2b(accr[tc][r] + bbr);
        }
    }
}

// ---------- node-centric attention + LN (+GELU) + residual ----------
__global__ __launch_bounds__(256) void k_node(
    const ushort* __restrict__ xl, const ushort* __restrict__ xr,
    const int* __restrict__ row_off, const int* __restrict__ adj_src, const float* __restrict__ adj_ea,
    const float* __restrict__ We, const float* __restrict__ att, const float* __restrict__ bias,
    const float* __restrict__ ln_g, const float* __restrict__ ln_b,
    float* __restrict__ h, int lanesPerHead, int apply_gelu)
{
    int wave = threadIdx.x >> 6, lane = threadIdx.x & 63;
    int n = blockIdx.x * 4 + wave;
    int c0 = 2 * lane, c1 = c0 + 1;

    float xr0, xr1;
    { uint u = *(const uint*)&xr[(size_t)n * 128 + c0]; xr0 = b2f((ushort)u); xr1 = b2f((ushort)(u >> 16)); }
    float we0 = We[c0], we1 = We[c1];
    float at0 = att[c0], at1 = att[c1];

    int s0 = row_off[n], s1 = row_off[n + 1];

    float m_run = -1e30f, l_run = 0.f, acc0 = 0.f, acc1 = 0.f;

    for (int base = s0; base < s1; base += 64) {
        int cnt = min(64, s1 - base);
        int srcl = 0; float eal = 0.f;
        if (base + lane < s1) { srcl = adj_src[base + lane]; eal = adj_ea[base + lane]; }
        for (int j = 0; j < cnt; j++) {
            int src = __shfl(srcl, j);
            float eav = __shfl(eal, j);
            uint u = *(const uint*)&xl[(size_t)src * 128 + c0];
            float xs0 = b2f((ushort)u), xs1 = b2f((ushort)(u >> 16));
            float m0 = xs0 + xr0 + eav * we0; m0 = (m0 >= 0.f) ? m0 : 0.2f * m0;
            float m1 = xs1 + xr1 + eav * we1; m1 = (m1 >= 0.f) ? m1 : 0.2f * m1;
            float p = m0 * at0 + m1 * at1;
            for (int off = 1; off < lanesPerHead; off <<= 1) p += __shfl_xor(p, off);
            float nm = fmaxf(m_run, p);
            float corr = __expf(m_run - nm);
            float pe = __expf(p - nm);
            l_run = l_run * corr + pe;
            acc0 = acc0 * corr + pe * xs0;
            acc1 = acc1 * corr + pe * xs1;
            m_run = nm;
        }
    }

    float inv = 1.0f / (l_run + 1e-16f);
    float o0 = acc0 * inv + bias[c0];
    float o1 = acc1 * inv + bias[c1];

    // LayerNorm over 128 channels (2 per lane)
    float s = o0 + o1;
    for (int off = 1; off < 64; off <<= 1) s += __shfl_xor(s, off);
    float mu = s * (1.f / 128.f);
    float d0 = o0 - mu, d1 = o1 - mu;
    float v = d0 * d0 + d1 * d1;
    for (int off = 1; off < 64; off <<= 1) v += __shfl_xor(v, off);
    float rstd = rsqrtf(v * (1.f / 128.f) + 1e-5f);
    o0 = d0 * rstd * ln_g[c0] + ln_b[c0];
    o1 = d1 * rstd * ln_g[c1] + ln_b[c1];

    if (apply_gelu) {
        o0 = 0.5f * o0 * (1.f + erff(o0 * 0.70710678118f));
        o1 = 0.5f * o1 * (1.f + erff(o1 * 0.70710678118f));
    }

    float2 hv = *(float2*)&h[(size_t)n * 128 + c0];
    hv.x += o0; hv.y += o1;
    *(float2*)&h[(size_t)n * 128 + c0] = hv;
}

// ---------- final: drop last node per graph, emit fp32 ----------
__global__ void k_out(const float* __restrict__ h, float* __restrict__ out) {
    int o = blockIdx.x * 256 + threadIdx.x;   // grid covers 128*511*128 exactly
    int c = o & 127;
    int row = o >> 7;
    int g = row / 511;
    int r = row - g * 511;
    out[o] = h[(size_t)(g * 512 + r) * 128 + c];
}

extern "C" void kernel_launch(void* const* d_in, const int* in_sizes, int n_in,
                              void* d_out, int out_size, void* d_ws, size_t ws_size,
                              hipStream_t stream) {
    const float* x        = (const float*)d_in[0];
    const int*   edge_src = (const int*)d_in[1];
    const int*   edge_dst = (const int*)d_in[2];
    const float* edge_attr= (const float*)d_in[3];
    const float* Wl       = (const float*)d_in[4];
    const float* bl       = (const float*)d_in[5];
    const float* Wr       = (const float*)d_in[6];
    const float* br       = (const float*)d_in[7];
    const float* We       = (const float*)d_in[8];
    const float* att      = (const float*)d_in[9];
    const float* bias_p   = (const float*)d_in[10];
    const float* ln_g     = (const float*)d_in[11];
    const float* ln_b     = (const float*)d_in[12];
    float* out = (float*)d_out;

    char* ws = (char*)d_ws;
    float*  h       = (float*)(ws + 0);                       // 33,554,432 B
    ushort* xl      = (ushort*)(ws + 33554432);               // 16,777,216 B
    ushort* xr      = (ushort*)(ws + 50331648);               // 16,777,216 B
    int*    adj_src = (int*)(ws + 67108864);                  //  4,456,448 B
    float*  adj_ea  = (float*)(ws + 71565312);                //  4,456,448 B
    int*    row_off = (int*)(ws + 76021760);                  //    262,148 B
    int*    cnt     = (int*)(ws + 76284160);                  //    262,144 B (also cursor)
    int*    bsum    = (int*)(ws + 76546304);                  //      1,024 B
    float*  sumbuf  = (float*)(ws + 76547584);                //          4 B
    ushort* WT      = (ushort*)(ws + 76547840);               //     65,536 B

    // init: h = x (fp32 copy)
    hipMemcpyAsync(h, x, (size_t)NN * DD * sizeof(float), hipMemcpyDeviceToDevice, stream);
    hipMemsetAsync(cnt, 0, NN * sizeof(int), stream);
    hipMemsetAsync(sumbuf, 0, sizeof(float), stream);
    k_sum<<<256, 256, 0, stream>>>(edge_attr, sumbuf);

    // CSR by dst (edges + self loops)
    k_hist<<<TOTE / 256, 256, 0, stream>>>(edge_dst, cnt);
    k_scanA<<<NN / 256, 256, 0, stream>>>(cnt, row_off, bsum);
    k_scanB<<<1, 256, 0, stream>>>(bsum);
    k_scanC<<<NN / 256, 256, 0, stream>>>(row_off, bsum, cnt);
    k_scatter<<<TOTE / 256, 256, 0, stream>>>(edge_src, edge_dst, edge_attr, sumbuf,
                                              cnt, adj_src, adj_ea);

    // 3 GATv2 layers
    for (int i = 0; i < 3; i++) {
        k_transpose<<<dim3(128, 2), 128, 0, stream>>>(Wl + i * 16384, Wr + i * 16384, WT);
        k_gemm<<<NN / 64, 256, 0, stream>>>(h, WT, bl + i * 128, br + i * 128, xl, xr);
        int lanesPerHead = (i < 2) ? 16 : 64;   // H=4 -> C=32 -> 16 lanes; H=1 -> 64 lanes
        int apply_gelu = (i < 2) ? 1 : 0;
        k_node<<<NN / 4, 256, 0, stream>>>(xl, xr, row_off, adj_src, adj_ea,
                                           We + i * 128, att + i * 128, bias_p + i * 128,
                                           ln_g + i * 128, ln_b + i * 128,
                                           h, lanesPerHead, apply_gelu);
    }

    // output: (128, 511, 128) fp32
    k_out<<<(128 * 511 * 128) / 256, 256, 0, stream>>>(h, out);
}